// Round 3
// baseline (584.879 us; speedup 1.0000x reference)
//
#include <hip/hip_runtime.h>
#include <math.h>

constexpr int B = 16, D = 128, N = 2048, M = 2048;
#define EPSF 1e-8f

// monotonic float -> uint mapping (preserves total order)
__device__ __forceinline__ unsigned int sortable_u32(float f) {
    unsigned int u = __float_as_uint(f);
    return (u & 0x80000000u) ? ~u : (u | 0x80000000u);
}
__device__ __forceinline__ float unsortable_f32(unsigned int s) {
    unsigned int u = (s & 0x80000000u) ? (s & 0x7FFFFFFFu) : ~s;
    return __uint_as_float(u);
}
__device__ __forceinline__ unsigned long long shfl_xor_u64(unsigned long long v, int mask) {
    unsigned int hi = (unsigned int)(v >> 32), lo = (unsigned int)v;
    hi = __shfl_xor(hi, mask); lo = __shfl_xor(lo, mask);
    return ((unsigned long long)hi << 32) | lo;
}

// ---------------------------------------------------------------------------
// init per-row argmax accumulator (ws is poisoned 0xAA before every launch)
// ---------------------------------------------------------------------------
__global__ void init_ws(unsigned long long* __restrict__ amax) {
    int i = blockIdx.x * 256 + threadIdx.x;
    if (i < B * N) amax[i] = 0ull;
}

// ---------------------------------------------------------------------------
// K1: logits GEMM, raw logits out + fused per-row max/argmax atomic.
// 128x128 tile, 256 threads, 8x8 per thread, BK=8.
// Per-thread cols split {tx*4..+3} u {64+tx*4..+3}: B-frag reads by the 16
// tx lanes cover 16 consecutive float4s = all 32 banks 2x (2-way = free),
// vs 4-way conflicts of the tx*8 mapping (R1: SQ_LDS_BANK_CONFLICT=1.7e7).
// Packed argmax key = sortable(x)<<32 | (M-1-col): max value wins, ties ->
// smallest col (matches jnp.argmax first-occurrence).
// ---------------------------------------------------------------------------
__global__ __launch_bounds__(256) void gemm_logits(
    const float* __restrict__ Ae, const float* __restrict__ Be,
    float* __restrict__ out, unsigned long long* __restrict__ amax)
{
    const int b  = blockIdx.z;
    const int n0 = blockIdx.y * 128;
    const int m0 = blockIdx.x * 128;
    const float* A  = Ae + (size_t)b * D * N;   // A[d][n]
    const float* Bm = Be + (size_t)b * D * M;   // B[d][m]
    float* C = out + (size_t)b * N * M;

    __shared__ float As[8][128];
    __shared__ float Bs[8][128];

    const int t  = threadIdx.x;
    const int lr = t >> 5;          // k-row for staging
    const int lc = (t & 31) * 4;    // col4 for staging
    const int tx = t & 15;          // m-dim coord
    const int ty = t >> 4;          // n-dim coord

    float acc[8][8];
#pragma unroll
    for (int i = 0; i < 8; ++i)
#pragma unroll
        for (int j = 0; j < 8; ++j) acc[i][j] = 0.f;

    for (int d0 = 0; d0 < D; d0 += 8) {
        const float4 av = *(const float4*)(A  + (size_t)(d0 + lr) * N + n0 + lc);
        const float4 bv = *(const float4*)(Bm + (size_t)(d0 + lr) * M + m0 + lc);
        *(float4*)(&As[lr][lc]) = av;
        *(float4*)(&Bs[lr][lc]) = bv;
        __syncthreads();
#pragma unroll
        for (int kk = 0; kk < 8; ++kk) {
            float a[8], bb[8];
            *(float4*)(&a[0])  = *(const float4*)(&As[kk][ty * 8]);
            *(float4*)(&a[4])  = *(const float4*)(&As[kk][ty * 8 + 4]);
            *(float4*)(&bb[0]) = *(const float4*)(&Bs[kk][tx * 4]);
            *(float4*)(&bb[4]) = *(const float4*)(&Bs[kk][64 + tx * 4]);
#pragma unroll
            for (int i = 0; i < 8; ++i)
#pragma unroll
                for (int j = 0; j < 8; ++j)
                    acc[i][j] = fmaf(a[i], bb[j], acc[i][j]);
        }
        __syncthreads();
    }

    // ---- epilogue: store raw logits + row max/argmax atomics ----
#pragma unroll
    for (int i = 0; i < 8; ++i) {
        const int row = n0 + ty * 8 + i;
        const int gr  = b * N + row;
        unsigned long long pk = 0ull;
#pragma unroll
        for (int j = 0; j < 8; ++j) {
            const int col = m0 + ((j < 4) ? tx * 4 + j : 64 + tx * 4 + (j - 4));
            unsigned long long key =
                ((unsigned long long)sortable_u32(acc[i][j]) << 32) |
                (unsigned int)(M - 1 - col);
            pk = pk > key ? pk : key;
        }
        size_t off = (size_t)row * M + m0;
        *(float4*)(C + off + tx * 4)      = make_float4(acc[i][0], acc[i][1], acc[i][2], acc[i][3]);
        *(float4*)(C + off + 64 + tx * 4) = make_float4(acc[i][4], acc[i][5], acc[i][6], acc[i][7]);

        // reduce packed key across the 16 tx lanes sharing this row
#pragma unroll
        for (int msk = 8; msk > 0; msk >>= 1) {
            unsigned long long o = shfl_xor_u64(pk, msk);
            pk = pk > o ? pk : o;
        }
        if (tx == 0) atomicMax(&amax[gr], pk);
    }
}

// ---------------------------------------------------------------------------
// K2: row softmax in place + entropy weight, max/argmax precomputed.
// One 256-thread block per row, 8 elems/thread. Reductions: 6-step wave
// shuffle + 4-slot LDS cross-wave (2 barriers total). Numerics match the
// verified R1 kernel: e=expf(x-max), p=e/S, ent=sum p*logf(p+1e-8).
// ---------------------------------------------------------------------------
__global__ __launch_bounds__(256) void softmax_rows(
    float* __restrict__ scores, const unsigned long long* __restrict__ amax,
    float* __restrict__ wout, int* __restrict__ idxout)
{
    const int row = blockIdx.x;     // 0..B*N-1
    float* p = scores + (size_t)row * M;
    const int t   = threadIdx.x;
    const int wid = t >> 6;

    __shared__ float redA[4], redB[4];

    const unsigned long long key = amax[row];
    const float rowmax = unsortable_f32((unsigned int)(key >> 32));
    const int   rowidx = (M - 1) - (int)(key & 0xFFFFFFFFull);

    float4 v0 = ((const float4*)p)[t];
    float4 v1 = ((const float4*)p)[t + 256];
    float e[8] = {expf(v0.x - rowmax), expf(v0.y - rowmax),
                  expf(v0.z - rowmax), expf(v0.w - rowmax),
                  expf(v1.x - rowmax), expf(v1.y - rowmax),
                  expf(v1.z - rowmax), expf(v1.w - rowmax)};

    float lsum = 0.f;
#pragma unroll
    for (int k = 0; k < 8; ++k) lsum += e[k];
#pragma unroll
    for (int m = 32; m > 0; m >>= 1) lsum += __shfl_xor(lsum, m);
    if ((t & 63) == 0) redA[wid] = lsum;
    __syncthreads();
    const float inv = 1.0f / (redA[0] + redA[1] + redA[2] + redA[3]);

    float ent = 0.f;
#pragma unroll
    for (int k = 0; k < 8; ++k) {
        float pk = e[k] * inv;
        e[k] = pk;
        ent += pk * logf(pk + EPSF);
    }
    ((float4*)p)[t]       = make_float4(e[0], e[1], e[2], e[3]);
    ((float4*)p)[t + 256] = make_float4(e[4], e[5], e[6], e[7]);

#pragma unroll
    for (int m = 32; m > 0; m >>= 1) ent += __shfl_xor(ent, m);
    if ((t & 63) == 0) redB[wid] = ent;
    __syncthreads();
    if (t == 0) {
        wout[row]   = -1.0f / ((redB[0] + redB[1] + redB[2] + redB[3]) + EPSF);
        idxout[row] = rowidx;
    }
}

// ---------------------------------------------------------------------------
// K3: per-batch weighted Kabsch (verified in R1). fp64 Jacobi SVD on H^T H.
// ---------------------------------------------------------------------------
__device__ inline float block_sum_256(float v, float* red, int t)
{
    red[t] = v; __syncthreads();
    for (int s = 128; s > 0; s >>= 1) { if (t < s) red[t] += red[t + s]; __syncthreads(); }
    float r = red[0]; __syncthreads();
    return r;
}

__global__ __launch_bounds__(256) void kabsch(
    const float* __restrict__ src, const float* __restrict__ tgt,
    const float* __restrict__ wraw, const int* __restrict__ idxv,
    float* __restrict__ Rout, float* __restrict__ tout)
{
    const int b = blockIdx.x;
    const int t = threadIdx.x;
    const float* S  = src  + (size_t)b * 3 * N;
    const float* T  = tgt  + (size_t)b * 3 * M;
    const float* w  = wraw + (size_t)b * N;
    const int*  idx = idxv + (size_t)b * N;

    __shared__ float red[256];

    float w8[8]; int i8[8];
    float s8[8][3], g8[8][3];
    float lsum = 0.f;
#pragma unroll
    for (int k = 0; k < 8; ++k) {
        int n = t + 256 * k;
        w8[k] = w[n];
        i8[k] = idx[n];
        lsum += w8[k];
#pragma unroll
        for (int i = 0; i < 3; ++i) {
            s8[k][i] = S[i * N + n];
            g8[k][i] = T[i * M + i8[k]];
        }
    }
    const float W = block_sum_256(lsum, red, t) + EPSF;

    float c[6] = {0, 0, 0, 0, 0, 0};
#pragma unroll
    for (int k = 0; k < 8; ++k) {
        float wn = w8[k] / W;
#pragma unroll
        for (int i = 0; i < 3; ++i) {
            c[i]     += wn * s8[k][i];
            c[3 + i] += wn * g8[k][i];
        }
    }
    float cen[6];
    for (int i = 0; i < 6; ++i) cen[i] = block_sum_256(c[i], red, t);

    float h[9] = {0};
#pragma unroll
    for (int k = 0; k < 8; ++k) {
        float wn = w8[k] / W;
        float a0 = s8[k][0] - cen[0], a1 = s8[k][1] - cen[1], a2 = s8[k][2] - cen[2];
        float b0 = (g8[k][0] - cen[3]) * wn;
        float b1 = (g8[k][1] - cen[4]) * wn;
        float b2 = (g8[k][2] - cen[5]) * wn;
        h[0] += a0 * b0; h[1] += a0 * b1; h[2] += a0 * b2;
        h[3] += a1 * b0; h[4] += a1 * b1; h[5] += a1 * b2;
        h[6] += a2 * b0; h[7] += a2 * b1; h[8] += a2 * b2;
    }
    float hr[9];
    for (int i = 0; i < 9; ++i) hr[i] = block_sum_256(h[i], red, t);

    if (t == 0) {
        double H[3][3];
        for (int i = 0; i < 3; ++i)
            for (int j = 0; j < 3; ++j)
                H[i][j] = (double)hr[i * 3 + j] + (i == j ? 1e-8 : 0.0);

        double A[3][3];
        for (int i = 0; i < 3; ++i)
            for (int j = 0; j < 3; ++j)
                A[i][j] = H[0][i] * H[0][j] + H[1][i] * H[1][j] + H[2][i] * H[2][j];

        double V[3][3] = {{1, 0, 0}, {0, 1, 0}, {0, 0, 1}};
        const int PP[3] = {0, 0, 1}, QQ[3] = {1, 2, 2};
        for (int sweep = 0; sweep < 30; ++sweep) {
            for (int r = 0; r < 3; ++r) {
                int p = PP[r], q = QQ[r];
                double apq = A[p][q];
                if (fabs(apq) < 1e-300) continue;
                double theta = (A[q][q] - A[p][p]) / (2.0 * apq);
                double tt = (theta >= 0 ? 1.0 : -1.0) /
                            (fabs(theta) + sqrt(theta * theta + 1.0));
                double cc = 1.0 / sqrt(tt * tt + 1.0);
                double ss = tt * cc;
                for (int k = 0; k < 3; ++k) {
                    double akp = A[k][p], akq = A[k][q];
                    A[k][p] = cc * akp - ss * akq;
                    A[k][q] = ss * akp + cc * akq;
                }
                for (int k = 0; k < 3; ++k) {
                    double apk = A[p][k], aqk = A[q][k];
                    A[p][k] = cc * apk - ss * aqk;
                    A[q][k] = ss * apk + cc * aqk;
                }
                for (int k = 0; k < 3; ++k) {
                    double vkp = V[k][p], vkq = V[k][q];
                    V[k][p] = cc * vkp - ss * vkq;
                    V[k][q] = ss * vkp + cc * vkq;
                }
            }
        }
        double ev[3] = {A[0][0], A[1][1], A[2][2]};
        int ord[3] = {0, 1, 2};
        for (int i = 0; i < 2; ++i)
            for (int j = i + 1; j < 3; ++j)
                if (ev[ord[j]] > ev[ord[i]]) { int tmp = ord[i]; ord[i] = ord[j]; ord[j] = tmp; }
        double Vs[3][3];
        for (int i = 0; i < 3; ++i)
            for (int j = 0; j < 3; ++j)
                Vs[i][j] = V[i][ord[j]];

        double U[3][3];
        for (int j = 0; j < 2; ++j) {
            double u0 = H[0][0] * Vs[0][j] + H[0][1] * Vs[1][j] + H[0][2] * Vs[2][j];
            double u1 = H[1][0] * Vs[0][j] + H[1][1] * Vs[1][j] + H[1][2] * Vs[2][j];
            double u2 = H[2][0] * Vs[0][j] + H[2][1] * Vs[1][j] + H[2][2] * Vs[2][j];
            if (j == 1) {
                double d0 = u0 * U[0][0] + u1 * U[1][0] + u2 * U[2][0];
                u0 -= d0 * U[0][0]; u1 -= d0 * U[1][0]; u2 -= d0 * U[2][0];
            }
            double nn = sqrt(u0 * u0 + u1 * u1 + u2 * u2);
            if (nn < 1e-150) {
                u0 = (j == 0) ? 1.0 : -U[1][0];
                u1 = (j == 0) ? 0.0 : U[0][0];
                u2 = 0.0;
                nn = sqrt(u0 * u0 + u1 * u1 + u2 * u2);
                if (nn < 1e-150) { u0 = 0; u1 = 0; u2 = 1; nn = 1; }
            }
            U[0][j] = u0 / nn; U[1][j] = u1 / nn; U[2][j] = u2 / nn;
        }
        U[0][2] = U[1][0] * U[2][1] - U[2][0] * U[1][1];
        U[1][2] = U[2][0] * U[0][1] - U[0][0] * U[2][1];
        U[2][2] = U[0][0] * U[1][1] - U[1][0] * U[0][1];

        double r[3][3];
        for (int i = 0; i < 3; ++i)
            for (int j = 0; j < 3; ++j)
                r[i][j] = Vs[i][0] * U[j][0] + Vs[i][1] * U[j][1] + Vs[i][2] * U[j][2];
        double det = r[0][0] * (r[1][1] * r[2][2] - r[1][2] * r[2][1])
                   - r[0][1] * (r[1][0] * r[2][2] - r[1][2] * r[2][0])
                   + r[0][2] * (r[1][0] * r[2][1] - r[1][1] * r[2][0]);

        double R[3][3];
        for (int i = 0; i < 3; ++i)
            for (int j = 0; j < 3; ++j)
                R[i][j] = Vs[i][0] * U[j][0] + Vs[i][1] * U[j][1] + det * Vs[i][2] * U[j][2];

        double tv[3];
        for (int i = 0; i < 3; ++i)
            tv[i] = (double)cen[3 + i]
                  - (R[i][0] * cen[0] + R[i][1] * cen[1] + R[i][2] * cen[2]);

        for (int i = 0; i < 3; ++i)
            for (int j = 0; j < 3; ++j)
                Rout[b * 9 + i * 3 + j] = (float)R[i][j];
        for (int i = 0; i < 3; ++i)
            tout[b * 3 + i] = (float)tv[i];
    }
}

// ---------------------------------------------------------------------------
extern "C" void kernel_launch(void* const* d_in, const int* in_sizes, int n_in,
                              void* d_out, int out_size, void* d_ws, size_t ws_size,
                              hipStream_t stream)
{
    const float* src_emb = (const float*)d_in[0];   // (B, D, N)
    const float* tgt_emb = (const float*)d_in[1];   // (B, D, M)
    const float* src     = (const float*)d_in[2];   // (B, 3, N)
    const float* tgt     = (const float*)d_in[3];   // (B, 3, M)

    float* out    = (float*)d_out;
    float* Rout   = out;                 // B*9
    float* tout   = out + B * 9;         // B*3
    float* scores = out + B * 12;        // B*N*M

    unsigned long long* amax  = (unsigned long long*)d_ws;          // B*N u64
    float*              wws   = (float*)(amax + B * N);             // B*N f32
    int*                idxws = (int*)(wws + B * N);                // B*N i32

    init_ws<<<(B * N + 255) / 256, 256, 0, stream>>>(amax);
    dim3 g1(M / 128, N / 128, B);
    gemm_logits<<<g1, 256, 0, stream>>>(src_emb, tgt_emb, scores, amax);
    softmax_rows<<<B * N, 256, 0, stream>>>(scores, amax, wws, idxws);
    kabsch<<<B, 256, 0, stream>>>(src, tgt, wws, idxws, Rout, tout);
}